// Round 5
// baseline (55.884 us; speedup 1.0000x reference)
//
#include <hip/hip_runtime.h>
#include <cstdint>

// NT-Xent: B=4096, D=128, N=8192, T=0.5
// loss = mean_i( log(sum_{j!=i} exp(sim_ij/T)) - sim_{i,(i+B)%N}/T )
//
// R4 -> R5 (theory: backend scheduler self-targets ~8 waves/EU -> 76-VGPR
// tier -> spills/reloads the 64-reg A array every tile; launch_bounds only
// sets a MINIMUM waves/EU so the heuristic is free to overshoot):
//  - amdgpu_waves_per_eu(3,3): pin occupancy target, VGPR budget 168,
//    demand ~135 -> A stays resident. Pins kept.

#define BROWS 4096
#define NROWS 8192
#define DIMS  128
#define ROWB  256          // bytes per bf16 row
#define CSPL  24           // column splits: 32 rowblocks x 24 = 768 blocks
#define CTILES 512         // 8192/16 column tiles
#define BRT   256          // rows per block (4 waves x 64)

typedef __attribute__((ext_vector_type(8))) __bf16    bf16x8;
typedef __attribute__((ext_vector_type(4))) float     f32x4;
typedef __attribute__((ext_vector_type(4))) uint32_t  u32x4;

#define K1F 2.8853900817779268f   // (1/T)*log2(e)
#define LN2F 0.69314718055994531f

__device__ __forceinline__ uint16_t f2bf(float f) {
    uint32_t u = __builtin_bit_cast(uint32_t, f);
    u = (u + 0x7FFFu + ((u >> 16) & 1u)) >> 16;
    return (uint16_t)u;
}
__device__ __forceinline__ float bf2f(uint16_t b) {
    return __builtin_bit_cast(float, ((uint32_t)b) << 16);
}

// ---- kernel 1: L2-normalize rows; emit znB = bf16(x^), znA = bf16(K1*x^) ----
__global__ __launch_bounds__(256) void k_normalize(
    const float* __restrict__ zi, const float* __restrict__ zj,
    uint16_t* __restrict__ znA, uint16_t* __restrict__ znB)
{
    int tid  = threadIdx.x;
    int lane = tid & 63;
    int wid  = tid >> 6;
    int li   = lane & 7;
    int row  = blockIdx.x * 32 + wid * 8 + (lane >> 3);

    const float* src = (row < BROWS) ? (zi + (size_t)row * DIMS)
                                     : (zj + (size_t)(row - BROWS) * DIMS);
    float4 v[4];
    const float4* s4 = (const float4*)(src + li * 16);
#pragma unroll
    for (int c = 0; c < 4; ++c) v[c] = s4[c];

    float ss = 0.f;
#pragma unroll
    for (int c = 0; c < 4; ++c)
        ss += v[c].x*v[c].x + v[c].y*v[c].y + v[c].z*v[c].z + v[c].w*v[c].w;
#pragma unroll
    for (int off = 1; off < 8; off <<= 1) ss += __shfl_xor(ss, off);

    float scale = 1.0f / fmaxf(sqrtf(ss), 1e-8f);

    float e[16];
#pragma unroll
    for (int c = 0; c < 4; ++c) {
        e[c*4+0] = v[c].x * scale; e[c*4+1] = v[c].y * scale;
        e[c*4+2] = v[c].z * scale; e[c*4+3] = v[c].w * scale;
    }
    uint32_t wB[8], wA[8];
#pragma unroll
    for (int q = 0; q < 8; ++q) {
        wB[q] = (uint32_t)f2bf(e[2*q])       | ((uint32_t)f2bf(e[2*q+1])       << 16);
        wA[q] = (uint32_t)f2bf(e[2*q] * K1F) | ((uint32_t)f2bf(e[2*q+1] * K1F) << 16);
    }
    uint4* dB = (uint4*)((char*)znB + (size_t)row * ROWB + li * 32);
    dB[0] = make_uint4(wB[0], wB[1], wB[2], wB[3]);
    dB[1] = make_uint4(wB[4], wB[5], wB[6], wB[7]);
    uint4* dA = (uint4*)((char*)znA + (size_t)row * ROWB + li * 32);
    dA[0] = make_uint4(wA[0], wA[1], wA[2], wA[3]);
    dA[1] = make_uint4(wA[4], wA[5], wA[6], wA[7]);
}

// ---- kernel 2: sim tiles via MFMA + sum(exp) per row ------------------------
// grid (32 rowblocks, 24 colsplits) = 768 blocks = 3/CU, fully resident.
// amdgpu_waves_per_eu(3,3): fixed 168-VGPR budget -> A (64 regs) resident.
__global__ __launch_bounds__(256)
__attribute__((amdgpu_waves_per_eu(3, 3)))
void k_simlse(
    const uint16_t* __restrict__ znA, const uint16_t* __restrict__ znB,
    float* __restrict__ partial)
{
    const char* zA = (const char*)znA;
    const char* zB = (const char*)znB;
    int tid  = threadIdx.x;
    int lane = tid & 63;
    int wid  = tid >> 6;
    int lo16 = lane & 15;
    int hi4  = lane >> 4;
    int rowBase = blockIdx.x * BRT + wid * 64;

    // A fragments (prescaled by K1): 4 row-tiles x 4 K-frags = 64 VGPR.
    u32x4 a[4][4];
#pragma unroll
    for (int rt = 0; rt < 4; ++rt) {
        const char* ap = zA + (size_t)(rowBase + rt * 16 + lo16) * ROWB + hi4 * 16;
#pragma unroll
        for (int kf = 0; kf < 4; ++kf)
            a[rt][kf] = *(const u32x4*)(ap + kf * 64);
    }
    // PIN: opaque identity (remat-proof defs)
#pragma unroll
    for (int rt = 0; rt < 4; ++rt)
#pragma unroll
        for (int kf = 0; kf < 4; ++kf)
            asm volatile("" : "+v"(a[rt][kf]));

    float rs[4][4];
#pragma unroll
    for (int rt = 0; rt < 4; ++rt)
#pragma unroll
        for (int r = 0; r < 4; ++r) rs[rt][r] = 0.f;

    // ragged col-tile range for this split (21 or 22 tiles)
    int t0 = (CTILES * blockIdx.y) / CSPL;
    int t1 = (CTILES * (blockIdx.y + 1)) / CSPL;
    int nt = t1 - t0;

    const char* bbase = zB + (size_t)(t0 * 16 + lo16) * ROWB + hi4 * 16;

#define LOADB(buf, t) do { const char* p_ = bbase + (size_t)(t) * (16 * ROWB); \
        buf[0] = *(const u32x4*)(p_);       buf[1] = *(const u32x4*)(p_ + 64);  \
        buf[2] = *(const u32x4*)(p_ + 128); buf[3] = *(const u32x4*)(p_ + 192); } while (0)

#define COMPUTE(buf) do {                                                        \
        _Pragma("unroll")                                                        \
        for (int rt = 0; rt < 4; ++rt) {                                         \
            f32x4 acc = {0.f, 0.f, 0.f, 0.f};                                    \
            _Pragma("unroll")                                                    \
            for (int kf = 0; kf < 4; ++kf)                                       \
                acc = __builtin_amdgcn_mfma_f32_16x16x32_bf16(                   \
                        __builtin_bit_cast(bf16x8, a[rt][kf]),                   \
                        __builtin_bit_cast(bf16x8, buf[kf]), acc, 0, 0, 0);      \
            _Pragma("unroll")                                                    \
            for (int r = 0; r < 4; ++r)                                          \
                rs[rt][r] += __builtin_amdgcn_exp2f(acc[r]);                     \
        }                                                                        \
    } while (0)

    u32x4 b0[4], b1[4];
    LOADB(b0, 0);
    LOADB(b1, 1);          // nt >= 21 always, so tile 1 exists

    int t = 0;
    for (; t + 2 < nt; t += 2) {
        COMPUTE(b0);
        LOADB(b0, t + 2);
        COMPUTE(b1);
        if (t + 3 < nt) LOADB(b1, t + 3);
    }
    COMPUTE(b0);
    if (t + 1 < nt) COMPUTE(b1);

#undef LOADB
#undef COMPUTE

    // reduce row-sums across the 16 column-lanes; write per-split partials
#pragma unroll
    for (int rt = 0; rt < 4; ++rt)
#pragma unroll
        for (int r = 0; r < 4; ++r) {
            float s = rs[rt][r];
            s += __shfl_xor(s, 1);  s += __shfl_xor(s, 2);
            s += __shfl_xor(s, 4);  s += __shfl_xor(s, 8);
            if (lo16 == 0) {
                int row = rowBase + rt * 16 + hi4 * 4 + r;
                partial[blockIdx.y * NROWS + row] = s;
            }
        }
}

// ---- kernel 3: per-row lse - pos, subtract diag, block partial sums --------
__global__ __launch_bounds__(256) void k_finalize(
    const uint16_t* __restrict__ znA, const uint16_t* __restrict__ znB,
    const float* __restrict__ partial, float* __restrict__ blocksum)
{
    int tid = threadIdx.x;
    int i = blockIdx.x * 256 + tid;

    float S = 0.f;
#pragma unroll
    for (int cs = 0; cs < CSPL; ++cs) S += partial[cs * NROWS + i];

    int j = (i + BROWS) & (NROWS - 1);
    const uint4* rAi = (const uint4*)((const char*)znA + (size_t)i * ROWB);
    const uint4* rBi = (const uint4*)((const char*)znB + (size_t)i * ROWB);
    const uint4* rBj = (const uint4*)((const char*)znB + (size_t)j * ROWB);
    float adot = 0.f;   // K1 * <zn_i, zn_j>
    float sdot = 0.f;   // K1 * <zn_i, zn_i>
#pragma unroll
    for (int c = 0; c < 16; ++c) {
        uint4 ua = rAi[c], ub = rBi[c], vb = rBj[c];
        const uint32_t* pa = (const uint32_t*)&ua;
        const uint32_t* pb = (const uint32_t*)&ub;
        const uint32_t* pv = (const uint32_t*)&vb;
#pragma unroll
        for (int q = 0; q < 4; ++q) {
            float a0 = bf2f((uint16_t)(pa[q] & 0xffffu)), a1 = bf2f((uint16_t)(pa[q] >> 16));
            float b0 = bf2f((uint16_t)(pb[q] & 0xffffu)), b1 = bf2f((uint16_t)(pb[q] >> 16));
            float v0 = bf2f((uint16_t)(pv[q] & 0xffffu)), v1 = bf2f((uint16_t)(pv[q] >> 16));
            adot += a0 * v0 + a1 * v1;
            sdot += a0 * b0 + a1 * b1;
        }
    }
    S -= __builtin_amdgcn_exp2f(sdot);                  // remove diagonal term
    float c = LN2F * (__builtin_amdgcn_logf(S) - adot); // ln(S) - pos/T

#pragma unroll
    for (int off = 1; off < 64; off <<= 1) c += __shfl_xor(c, off);
    __shared__ float wsum[4];
    int lane = tid & 63, wid = tid >> 6;
    if (lane == 0) wsum[wid] = c;
    __syncthreads();
    if (tid == 0) blocksum[blockIdx.x] = wsum[0] + wsum[1] + wsum[2] + wsum[3];
}

// ---- kernel 4: final scalar -------------------------------------------------
__global__ __launch_bounds__(64) void k_reduce(
    const float* __restrict__ blocksum, float* __restrict__ out)
{
    int tid = threadIdx.x;
    float v = (tid < 32) ? blocksum[tid] : 0.f;
#pragma unroll
    for (int off = 1; off < 64; off <<= 1) v += __shfl_xor(v, off);
    if (tid == 0) out[0] = v * (1.0f / (float)NROWS);
}

extern "C" void kernel_launch(void* const* d_in, const int* in_sizes, int n_in,
                              void* d_out, int out_size, void* d_ws, size_t ws_size,
                              hipStream_t stream)
{
    const float* zi = (const float*)d_in[0];
    const float* zj = (const float*)d_in[1];
    float* out = (float*)d_out;

    char* ws = (char*)d_ws;
    uint16_t* znA      = (uint16_t*)ws;                                   // 2 MB
    uint16_t* znB      = (uint16_t*)(ws + (size_t)NROWS * ROWB);          // 2 MB
    float*    partial  = (float*)(ws + 2 * (size_t)NROWS * ROWB);         // 768 KB
    float*    blocksum = (float*)(ws + 2 * (size_t)NROWS * ROWB
                                     + (size_t)CSPL * NROWS * 4);

    k_normalize<<<dim3(256), dim3(256), 0, stream>>>(zi, zj, znA, znB);
    k_simlse  <<<dim3(32, CSPL), dim3(256), 0, stream>>>(znA, znB, partial);
    k_finalize<<<dim3(32), dim3(256), 0, stream>>>(znA, znB, partial, blocksum);
    k_reduce  <<<dim3(1), dim3(64), 0, stream>>>(blocksum, out);
}